// Round 5
// baseline (49961.050 us; speedup 1.0000x reference)
//
#include <hip/hip_runtime.h>
#include <hip/hip_bf16.h>
#include <math.h>
#include <stdio.h>

// EncoDecLSTM: B=256, T=512, F=128, U=1024.
// R5 = R4 with the fence builtin fixed (__builtin_amdgcn_fence, "agent").
// Single persistent kernel for all 1024 recurrence steps + chunked proj.
// 256 blocks x 256 thr (1 block/CU -> all co-resident), device-wide barrier
// via agent-scope atomics. Numerics identical to R3 (3-limb bf16 = fp32-grade;
// decoder Jacobian amplifies per-step noise ~1e2-1e5x, so plain bf16 fails).
// Wave tile 32x32 (2x2 MFMA tiles): 12 loads -> 24 MFMA per kc.
// x is split3'd in-register from raw fp32 (no 100MB pre-pack buffer).

typedef __attribute__((ext_vector_type(8))) short short8;   // 8 x bf16
typedef __attribute__((ext_vector_type(4))) float f32x4;

#define MFMA(a, b, c) __builtin_amdgcn_mfma_f32_16x16x32_bf16(a, b, c, 0, 0, 0)

// 6 limb products (hh, hm, mh, mm, hl, lh): residual ~2^-24
#define LIMB6(acc, A0, A1, A2, B0, B1, B2) \
  acc = MFMA(A0, B0, acc); acc = MFMA(A0, B1, acc); \
  acc = MFMA(A1, B0, acc); acc = MFMA(A1, B1, acc); \
  acc = MFMA(A0, B2, acc); acc = MFMA(A2, B0, acc);

__device__ __forceinline__ short f2bf(float f) {
  union { __hip_bfloat16 h; short s; } u;
  u.h = __float2bfloat16(f);
  return u.s;
}
__device__ __forceinline__ void split3(float x, short& a, short& b, short& c) {
  union { __hip_bfloat16 h; short s; } u;
  u.h = __float2bfloat16(x); a = u.s;
  float r1 = x - __bfloat162float(u.h);
  u.h = __float2bfloat16(r1); b = u.s;
  float r2 = r1 - __bfloat162float(u.h);
  u.h = __float2bfloat16(r2); c = u.s;
}
__device__ __forceinline__ float sigm(float x) { return 1.0f / (1.0f + expf(-x)); }

// ---------------------------------------------------------------------------
// pack_w: identical layouts to R3 (PASSED). B-fragment layout, 1 or 3 limbs.
// ---------------------------------------------------------------------------
__global__ void pack_w(const float* __restrict__ a, const float* __restrict__ b,
                       short8* __restrict__ dst, int KC, int mode, int ncols,
                       int limbs) {
  int gid = blockIdx.x * 256 + threadIdx.x;
  int lane = gid & 63;
  int kc = (gid >> 6) % KC;
  int nt = gid / (KC * 64);
  int u16 = lane & 15, kq = lane >> 4;
  int kbase = kc * 32 + kq * 8;
  int col;
  if (mode <= 1) { int g = nt & 3, ub = nt >> 2; col = g * 1024 + ub * 16 + u16; }
  else col = nt * 16 + u16;
  short8 v0, v1, v2;
#pragma unroll
  for (int j = 0; j < 8; ++j) {
    int k = kbase + j;
    float x;
    if (mode == 0)      x = a[(size_t)k * 4096 + col] + b[(size_t)k * 4096 + col];
    else if (mode == 1) x = (k < 1024) ? a[(size_t)k * 4096 + col]
                                       : b[(size_t)(k - 1024) * 4096 + col];
    else                x = a[(size_t)k * ncols + col];
    short sa, sb, sc; split3(x, sa, sb, sc);
    v0[j] = sa; v1[j] = sb; v2[j] = sc;
  }
  if (limbs == 3) {
    size_t base = (size_t)(nt * KC + kc) * 3 * 64 + lane;
    dst[base] = v0; dst[base + 64] = v1; dst[base + 128] = v2;
  } else {
    dst[(size_t)(nt * KC + kc) * 64 + lane] = v0;
  }
}

__global__ void zero_f(float* p, int n) {
  int i = blockIdx.x * 256 + threadIdx.x;
  if (i < n) p[i] = 0.f;
}

// Device-wide barrier: monotonic generation flags, agent-scope.
__device__ __forceinline__ void gbar(int* flags, int bid, int gen) {
  __syncthreads();                       // all waves drained
  if (threadIdx.x == 0) {
    __builtin_amdgcn_fence(__ATOMIC_RELEASE, "agent");
    __hip_atomic_store(&flags[bid], gen, __ATOMIC_RELAXED, __HIP_MEMORY_SCOPE_AGENT);
  }
  int v;
  do {
    v = __hip_atomic_load(&flags[threadIdx.x], __ATOMIC_RELAXED,
                          __HIP_MEMORY_SCOPE_AGENT);
    if (v < gen) __builtin_amdgcn_s_sleep(2);
  } while (v < gen);
  __builtin_amdgcn_fence(__ATOMIC_ACQUIRE, "agent");
  __syncthreads();
}

// ---------------------------------------------------------------------------
// The persistent kernel: encoder 512 steps + decoder 512 steps + 16 proj
// chunks. Block = 64 rows (rb) x 64 gate-cols (ub: 16 units x 4 gates).
// 4 waves, each a 32x32 tile (2x2 of 16x16): per kc 12 loads -> 24 MFMA.
// ---------------------------------------------------------------------------
__global__ __launch_bounds__(256) void lstm_all(
    const float* __restrict__ x,
    const short8* __restrict__ Wenc, const float* __restrict__ encb,
    const short8* __restrict__ Wdec, const float* __restrict__ decb,
    const short8* __restrict__ W1, const float* __restrict__ b1,
    const short8* __restrict__ W2, const float* __restrict__ b2,
    short8* __restrict__ Hb, short8* __restrict__ Hring,
    int* __restrict__ flags, float* __restrict__ out) {

  __shared__ union {
    float zt[64][68];          // gate pre-activations  (17.4 KB)
    short a1f[4][8][512];      // proj intermediate     (32 KB)
  } sh;

  int tid = threadIdx.x, bid = blockIdx.x;
  int lane = tid & 63, wv = tid >> 6;
  int wr = wv & 1, wc = wv >> 1;
  int xcd = bid & 7, idx = bid >> 3;
  int rb = idx >> 3;              // row-block  [0,4)
  int ub = xcd * 8 + (idx & 7);   // unit-block [0,64): per-XCD contiguous W slice
  int u16 = lane & 15, quad = lane >> 4;
  int gen = 0;

  float c8[8];                    // cell state: tid<128 owns (row tid>>1, octet tid&1)
#pragma unroll
  for (int j = 0; j < 8; ++j) c8[j] = 0.f;

  const size_t H3 = (size_t)16 * 32 * 3 * 64;   // short8 per 3-limb h-state
  const size_t HR = (size_t)16 * 32 * 64;       // short8 per hi-limb h-state
  const int mt0 = rb * 4 + wr * 2;
  const int nt0 = ub * 4 + wc * 2;

  for (int step = 0; step < 1024; ++step) {
    const bool enc = step < 512;
    const int t = enc ? step : step - 512;
    const short8* A = Hb + (size_t)(step & 1) * H3;
    short8* Ho = Hb + (size_t)((step + 1) & 1) * H3;
    const short8* W = enc ? Wenc : Wdec;
    const float* bias = enc ? encb : decb;
    const int KC = enc ? 36 : 32;

    const f32x4 z4 = {0.f, 0.f, 0.f, 0.f};
    f32x4 acc00 = z4, acc01 = z4, acc10 = z4, acc11 = z4;
    const short8* Ap0 = A + (size_t)mt0 * 32 * 3 * 64 + lane;
    const short8* Ap1 = A + (size_t)(mt0 + 1) * 32 * 3 * 64 + lane;
    const short8* Bp0 = W + (size_t)nt0 * KC * 3 * 64 + lane;
    const short8* Bp1 = W + (size_t)(nt0 + 1) * KC * 3 * 64 + lane;

    for (int kc = 0; kc < 32; ++kc) {
      short8 a00 = Ap0[kc * 192], a01 = Ap0[kc * 192 + 64], a02 = Ap0[kc * 192 + 128];
      short8 a10 = Ap1[kc * 192], a11 = Ap1[kc * 192 + 64], a12 = Ap1[kc * 192 + 128];
      short8 b00 = Bp0[kc * 192], b01 = Bp0[kc * 192 + 64], b02 = Bp0[kc * 192 + 128];
      short8 b10 = Bp1[kc * 192], b11 = Bp1[kc * 192 + 64], b12 = Bp1[kc * 192 + 128];
      LIMB6(acc00, a00, a01, a02, b00, b01, b02);
      LIMB6(acc01, a00, a01, a02, b10, b11, b12);
      LIMB6(acc10, a10, a11, a12, b00, b01, b02);
      LIMB6(acc11, a10, a11, a12, b10, b11, b12);
    }
    if (enc) {   // x-part: kc 32..35, A built in-register from raw fp32 x
#pragma unroll
      for (int kx = 0; kx < 4; ++kx) {
        int kc = 32 + kx;
        short8 xa0[2], xa1[2], xa2[2];
#pragma unroll
        for (int i = 0; i < 2; ++i) {
          const float* xp = x + ((size_t)((mt0 + i) * 16 + u16) * 512 + t) * 128
                              + kx * 32 + quad * 8;
#pragma unroll
          for (int j = 0; j < 8; ++j) {
            short sa, sb, sc; split3(xp[j], sa, sb, sc);
            xa0[i][j] = sa; xa1[i][j] = sb; xa2[i][j] = sc;
          }
        }
        short8 b00 = Bp0[kc * 192], b01 = Bp0[kc * 192 + 64], b02 = Bp0[kc * 192 + 128];
        short8 b10 = Bp1[kc * 192], b11 = Bp1[kc * 192 + 64], b12 = Bp1[kc * 192 + 128];
        LIMB6(acc00, xa0[0], xa1[0], xa2[0], b00, b01, b02);
        LIMB6(acc01, xa0[0], xa1[0], xa2[0], b10, b11, b12);
        LIMB6(acc10, xa0[1], xa1[1], xa2[1], b00, b01, b02);
        LIMB6(acc11, xa0[1], xa1[1], xa2[1], b10, b11, b12);
      }
    }

    float bv0 = bias[(wc * 2 + 0) * 1024 + ub * 16 + u16];
    float bv1 = bias[(wc * 2 + 1) * 1024 + ub * 16 + u16];
    // C/D layout: col = lane&15, row = quad*4 + reg  (m89/m91-verified)
#pragma unroll
    for (int r = 0; r < 4; ++r) {
      sh.zt[wr * 32 + 0 * 16 + quad * 4 + r][(wc * 2 + 0) * 16 + u16] = acc00[r] + bv0;
      sh.zt[wr * 32 + 0 * 16 + quad * 4 + r][(wc * 2 + 1) * 16 + u16] = acc01[r] + bv1;
      sh.zt[wr * 32 + 1 * 16 + quad * 4 + r][(wc * 2 + 0) * 16 + u16] = acc10[r] + bv0;
      sh.zt[wr * 32 + 1 * 16 + quad * 4 + r][(wc * 2 + 1) * 16 + u16] = acc11[r] + bv1;
    }
    __syncthreads();

    if (tid < 128) {
      int r = tid >> 1, s = tid & 1;     // row 0..63, u-octet 0..1
      int m = rb * 64 + r;
      int ubase = ub * 16 + s * 8;
      short8 h0, h1, h2;
#pragma unroll
      for (int j = 0; j < 8; ++j) {
        int uu = s * 8 + j;
        float iv = sh.zt[r][uu];
        float fv = sh.zt[r][16 + uu];
        float gv = sh.zt[r][32 + uu];
        float ov = sh.zt[r][48 + uu];
        float cn = sigm(fv) * c8[j] + sigm(iv) * tanhf(gv);
        c8[j] = cn;
        float hval = sigm(ov) * tanhf(cn);
        short sa, sb, sc; split3(hval, sa, sb, sc);
        h0[j] = sa; h1[j] = sb; h2[j] = sc;
      }
      int mtw = m >> 4, r16 = m & 15;
      int kcw = ubase >> 5, ko = ubase & 31;
      int lane_t = r16 + 16 * (ko >> 3);
      size_t base = ((size_t)(mtw * 32 + kcw) * 3) * 64 + lane_t;
      Ho[base] = h0; Ho[base + 64] = h1; Ho[base + 128] = h2;
      if (!enc)
        Hring[(size_t)(t & 31) * HR + (size_t)(mtw * 32 + kcw) * 64 + lane_t] = h0;
    }

    gbar(flags, bid, ++gen);

    // ---- projection chunk (every 32 decoder steps), blocks 0..127 active ----
    if (!enc && (t & 31) == 31) {
      if (bid < 128) {
        int tloc = bid >> 2, mb = bid & 3;
        int tt = (t - 31) + tloc;
        const short8* Ah = Hring + (size_t)tloc * HR;
        int pmt0 = mb * 4 + wr * 2;
        const f32x4 pz = {0.f, 0.f, 0.f, 0.f};
        f32x4 acc2[2][4];
#pragma unroll
        for (int i = 0; i < 2; ++i)
#pragma unroll
          for (int jj = 0; jj < 4; ++jj) acc2[i][jj] = pz;

        for (int q = 0; q < 4; ++q) {
          f32x4 acc1[2][8];
#pragma unroll
          for (int i = 0; i < 2; ++i)
#pragma unroll
            for (int n = 0; n < 8; ++n) acc1[i][n] = pz;
          for (int kc = 0; kc < 32; ++kc) {
            short8 av0 = Ah[(size_t)(pmt0 * 32 + kc) * 64 + lane];
            short8 av1 = Ah[(size_t)((pmt0 + 1) * 32 + kc) * 64 + lane];
#pragma unroll
            for (int n = 0; n < 8; ++n) {
              int nt = q * 16 + wc * 8 + n;
              short8 bv = W1[(size_t)(nt * 32 + kc) * 64 + lane];
              acc1[0][n] = MFMA(av0, bv, acc1[0][n]);
              acc1[1][n] = MFMA(av1, bv, acc1[1][n]);
            }
          }
          __syncthreads();
#pragma unroll
          for (int i = 0; i < 2; ++i)
#pragma unroll
            for (int n = 0; n < 8; ++n)
#pragma unroll
              for (int r = 0; r < 4; ++r) {
                int rl = wr * 32 + i * 16 + quad * 4 + r;
                int nloc = wc * 128 + n * 16 + u16;
                float v = fmaxf(acc1[i][n][r] + b1[q * 256 + nloc], 0.f);
                int mtl = rl >> 4, r16 = rl & 15;
                int kcl = nloc >> 5, ko = nloc & 31;
                sh.a1f[mtl][kcl][(r16 + 16 * (ko >> 3)) * 8 + (ko & 7)] = f2bf(v);
              }
          __syncthreads();
          for (int kcl = 0; kcl < 8; ++kcl) {
            short8 av0 = *(const short8*)&sh.a1f[wr * 2 + 0][kcl][lane * 8];
            short8 av1 = *(const short8*)&sh.a1f[wr * 2 + 1][kcl][lane * 8];
#pragma unroll
            for (int jj = 0; jj < 4; ++jj) {
              int nt2 = wc * 4 + jj;
              short8 bv = W2[(size_t)(nt2 * 32 + q * 8 + kcl) * 64 + lane];
              acc2[0][jj] = MFMA(av0, bv, acc2[0][jj]);
              acc2[1][jj] = MFMA(av1, bv, acc2[1][jj]);
            }
          }
        }
#pragma unroll
        for (int i = 0; i < 2; ++i)
#pragma unroll
          for (int jj = 0; jj < 4; ++jj)
#pragma unroll
            for (int r = 0; r < 4; ++r) {
              int rl = wr * 32 + i * 16 + quad * 4 + r;
              int f = wc * 64 + jj * 16 + u16;
              int bb = mb * 64 + rl;
              out[((size_t)bb * 512 + tt) * 128 + f] = acc2[i][jj][r] + b2[f];
            }
      }
      gbar(flags, bid, ++gen);   // Hring reusable only after proj done
    }
  }
}

extern "C" void kernel_launch(void* const* d_in, const int* in_sizes, int n_in,
                              void* d_out, int out_size, void* d_ws, size_t ws_size,
                              hipStream_t stream) {
  const float* x     = (const float*)d_in[0];
  const float* encWx = (const float*)d_in[1];
  const float* encWh = (const float*)d_in[2];
  const float* encb  = (const float*)d_in[3];
  const float* decWx = (const float*)d_in[4];
  const float* decWh = (const float*)d_in[5];
  const float* decb  = (const float*)d_in[6];
  const float* d1W   = (const float*)d_in[7];
  const float* d1b   = (const float*)d_in[8];
  const float* d2W   = (const float*)d_in[9];
  const float* d2b   = (const float*)d_in[10];

  char* ws = (char*)d_ws;
  size_t off = 0;
  short8* Wenc = (short8*)(ws + off); off += (size_t)256 * 36 * 3 * 64 * 16;  // 28.3 MB
  short8* Wdec = (short8*)(ws + off); off += (size_t)256 * 32 * 3 * 64 * 16;  // 25.2 MB
  short8* W1   = (short8*)(ws + off); off += (size_t)64 * 32 * 64 * 16;       //  2.10 MB
  short8* W2   = (short8*)(ws + off); off += (size_t)8 * 32 * 64 * 16;        //  0.26 MB
  short8* Hb   = (short8*)(ws + off); off += (size_t)2 * 16 * 32 * 3 * 64 * 16;  // 3.15 MB
  short8* Hring= (short8*)(ws + off); off += (size_t)32 * 16 * 32 * 64 * 16;     // 16.78 MB
  int*   flags = (int*)(ws + off);    off += 1024;
  (void)in_sizes; (void)n_in; (void)out_size;  // total ~75.8 MB
  if (ws_size < off) {
    fprintf(stderr, "kernel_launch: ws_size=%zu < needed=%zu -- aborting launch\n",
            ws_size, off);
    return;
  }

  pack_w<<<2304, 256, 0, stream>>>(encWh, encWx, Wenc, 36, 1, 4096, 3);
  pack_w<<<2048, 256, 0, stream>>>(decWx, decWh, Wdec, 32, 0, 4096, 3);
  pack_w<<<512, 256, 0, stream>>>(d1W, nullptr, W1, 32, 2, 1024, 1);
  pack_w<<<64, 256, 0, stream>>>(d2W, nullptr, W2, 32, 3, 128, 1);
  zero_f<<<3072, 256, 0, stream>>>((float*)Hb, 786432);   // h0 = 0 (both buffers)
  zero_f<<<1, 256, 0, stream>>>((float*)flags, 256);      // barrier generation = 0

  lstm_all<<<256, 256, 0, stream>>>(x, Wenc, encb, Wdec, decb, W1, d1b, W2, d2b,
                                    Hb, Hring, flags, (float*)d_out);
}